// Round 13
// baseline (64.614 us; speedup 1.0000x reference)
//
#include <hip/hip_runtime.h>
#include <hip/hip_bf16.h>

#define T_TOKENS 2048
#define DIM 256
#define NLEV 8
#define NCONV 4080   // 255 nodes * 16 tiles

using bf16x8 = __attribute__((ext_vector_type(8))) short;
using f32x4  = __attribute__((ext_vector_type(4))) float;

__device__ __forceinline__ unsigned short f2bf(float f) {
    union { float f; unsigned u; } v; v.f = f;
    unsigned r = v.u + 0x7FFFu + ((v.u >> 16) & 1u);   // RNE
    return (unsigned short)(r >> 16);
}

// ---------------- Kernel 1: fused {w2 transpose-convert} + {routing + xbf} ----------------
// blocks [0, 4080): tile transpose w2[node][k][c] fp32 -> w2bfT[node][c][k] bf16.
//   Tile = 64k x 64c. Coalesced float4 reads, LDS transpose, coalesced 16B writes.
// blocks [4080, 4592): routing (exact fp32) + bf16 x emission, as proven.
__global__ __launch_bounds__(256) void fused_kernel(
    const float* __restrict__ x, const float* __restrict__ w1s,
    const float* __restrict__ b1s, const float* __restrict__ w2s,
    float* __restrict__ pw, int* __restrict__ pc,
    unsigned short* __restrict__ xbf, unsigned short* __restrict__ w2bfT)
{
    __shared__ unsigned short ldsT[64][80];   // pad 80: 160B row stride, 16B-aligned

    if (blockIdx.x < NCONV) {
        int node = blockIdx.x >> 4;
        int tile = blockIdx.x & 15;
        int k0 = (tile >> 2) * 64, c0 = (tile & 3) * 64;
        const float* src = w2s + ((size_t)node << 16);
        int tid = threadIdx.x;
        int rb = tid >> 4, c4 = tid & 15;
        #pragma unroll
        for (int i = 0; i < 4; ++i) {
            int row = rb + i * 16;
            float4 v = *reinterpret_cast<const float4*>(src + (size_t)(k0 + row) * 256 + c0 + c4 * 4);
            ldsT[c4 * 4 + 0][row] = f2bf(v.x);
            ldsT[c4 * 4 + 1][row] = f2bf(v.y);
            ldsT[c4 * 4 + 2][row] = f2bf(v.z);
            ldsT[c4 * 4 + 3][row] = f2bf(v.w);
        }
        __syncthreads();
        int c = tid >> 2, ko = (tid & 3) * 16;
        unsigned short* dst = w2bfT + ((size_t)node << 16) + (size_t)(c0 + c) * 256 + k0 + ko;
        uint4 t0 = *reinterpret_cast<const uint4*>(&ldsT[c][ko]);
        uint4 t1 = *reinterpret_cast<const uint4*>(&ldsT[c][ko + 8]);
        *reinterpret_cast<uint4*>(dst)     = t0;
        *reinterpret_cast<uint4*>(dst + 8) = t1;
        return;
    }

    // ----- routing part -----
    int bid = blockIdx.x - NCONV;
    int wave = threadIdx.x >> 6;
    int lane = threadIdx.x & 63;
    int t = bid * 4 + wave;    // 512 blocks -> t < 2048

    const float4 xv = *reinterpret_cast<const float4*>(x + (size_t)t * DIM + lane * 4);

    ushort4 xb;
    xb.x = f2bf(xv.x); xb.y = f2bf(xv.y); xb.z = f2bf(xv.z); xb.w = f2bf(xv.w);
    *reinterpret_cast<ushort4*>(xbf + (size_t)t * DIM + lane * 4) = xb;

    int p = 1;
    float keep = 0.0f;
    #pragma unroll
    for (int lvl = 0; lvl < NLEV; ++lvl) {
        int node = p - 1;
        const float4 wv = *reinterpret_cast<const float4*>(w1s + (size_t)node * DIM + lane * 4);
        float s = xv.x * wv.x + xv.y * wv.y + xv.z * wv.z + xv.w * wv.w;
        #pragma unroll
        for (int off = 32; off; off >>= 1) s += __shfl_xor(s, off);
        float score = s + b1s[node];
        float a = fabsf(score);
        float g = a * 0.5f * (1.0f + erff(a * 0.70710678118654752f));  // exact GELU
        if (lane == lvl) keep = g;
        int choice = (score > 0.0f) ? 1 : 0;   // sign(0)->choice 0 matches ref
        p = 2 * p + choice;
    }
    if (lane < NLEV) pw[(size_t)t * NLEV + lane] = keep;
    if (lane == 0) pc[t] = p;
}

// ---------------- Kernel 2: counting sort + unit enumeration (1 block) ----------------
__global__ __launch_bounds__(256) void sort_kernel(
    const int* __restrict__ pc,
    int* __restrict__ order, unsigned* __restrict__ units, int* __restrict__ ucount)
{
    __shared__ int hist[256];
    __shared__ int offs[256];
    __shared__ int cums[257];
    __shared__ int wpart[4];
    int tid = threadIdx.x;
    hist[tid] = 0;
    __syncthreads();

    int myPc[8];
    #pragma unroll
    for (int i = 0; i < 8; ++i) {
        int t = tid * 8 + i;
        myPc[i] = pc[t];
        atomicAdd(&hist[myPc[i] - 256], 1);
    }
    __syncthreads();

    if (tid < 64) {
        int lane = tid;
        int v0 = hist[lane * 4 + 0], v1 = hist[lane * 4 + 1];
        int v2 = hist[lane * 4 + 2], v3 = hist[lane * 4 + 3];
        int sum = v0 + v1 + v2 + v3;
        int scan = sum;
        #pragma unroll
        for (int off = 1; off < 64; off <<= 1) {
            int n = __shfl_up(scan, off);
            if (lane >= off) scan += n;
        }
        int excl = scan - sum;
        offs[lane * 4 + 0] = excl;
        offs[lane * 4 + 1] = excl + v0;
        offs[lane * 4 + 2] = excl + v0 + v1;
        offs[lane * 4 + 3] = excl + v0 + v1 + v2;
    }
    __syncthreads();

    cums[tid] = offs[tid];
    if (tid == 0) cums[256] = T_TOKENS;
    __syncthreads();

    #pragma unroll
    for (int i = 0; i < 8; ++i) {
        int t = tid * 8 + i;
        int bin = myPc[i] - 256;
        int pos = atomicAdd(&offs[bin], 1);
        order[pos] = t;
    }

    int nch = 0, s = 0, e = 0, l = 0;
    if (tid < 255) {
        int q = tid + 1;
        l = 31 - __clz(q);
        int shift = 8 - l;
        int lo = (q << shift) - 256;
        int hi = ((q + 1) << shift) - 256;
        s = cums[lo];
        e = cums[hi];
        nch = (e - s + 63) >> 6;
    }
    int lane = tid & 63, w = tid >> 6;
    int scan = nch;
    #pragma unroll
    for (int off = 1; off < 64; off <<= 1) {
        int n = __shfl_up(scan, off);
        if (lane >= off) scan += n;
    }
    if (lane == 63) wpart[w] = scan;
    __syncthreads();
    int pre = 0;
    for (int k = 0; k < w; ++k) pre += wpart[k];
    int base = pre + scan - nch;
    for (int j = 0; j < nch; ++j) {
        int st = s + j * 64;
        int c = e - st; if (c > 64) c = 64;
        units[base + j] = (unsigned)tid | ((unsigned)l << 8) |
                          ((unsigned)st << 11) | ((unsigned)c << 22);
    }
    if (tid == 255) *ucount = pre + scan;
}

// ---------------- Kernel 3: per-(unit, 16-col strip) wave GEMM; B via contiguous dwordx4 ----------------
// B frags: 8 x 16B contiguous loads per lane from k-major w2bfT (L3-hot).
// A direct from bf16 x with 2-deep named-buffer pipeline. No LDS/barriers/atomics.
__global__ __launch_bounds__(256, 2) void out_kernel(
    const unsigned short* __restrict__ xbf, const unsigned short* __restrict__ w2bfT,
    const float* __restrict__ b2s, const float* __restrict__ pw,
    const int* __restrict__ order, const unsigned* __restrict__ units,
    const int* __restrict__ ucount, float* __restrict__ lvlbuf)
{
    int u = blockIdx.x >> 2;
    if (u >= *ucount) return;
    unsigned d = units[u];
    int node  = (int)(d & 255u);
    int lvl   = (int)((d >> 8) & 7u);
    int start = (int)((d >> 11) & 2047u);
    int cnt   = (int)((d >> 22) & 127u);

    int wv = threadIdx.x >> 6, lane = threadIdx.x & 63;
    int strip = (blockIdx.x & 3) * 4 + wv;   // 0..15
    int colbase = strip * 16;
    int l15 = lane & 15, kg = lane >> 4;

    int tok[4];
    #pragma unroll
    for (int m = 0; m < 4; ++m) {
        int r = m * 16 + l15;
        tok[m] = order[start + (r < cnt ? r : cnt - 1)];
    }

    // B fragments: bfr[ks] = w2bfT[node][colbase+l15][ks*32 + kg*8 .. +7]  (16B contiguous)
    const unsigned short* w2c = w2bfT + ((size_t)node << 16) + (size_t)(colbase + l15) * 256 + kg * 8;
    bf16x8 bfr[8];
    #pragma unroll
    for (int ks = 0; ks < 8; ++ks)
        bfr[ks] = *reinterpret_cast<const bf16x8*>(w2c + ks * 32);

    float bias = b2s[((size_t)node << 8) + colbase + l15];
    float* dst = lvlbuf + ((size_t)lvl << 19);   // 2048*256 per level
    int nmt = (cnt + 15) >> 4;

    bf16x8 aA[8], aB[8];
    auto loadA = [&](int m, bf16x8 (&a)[8]) {
        const unsigned short* xp = xbf + ((size_t)tok[m] << 8) + kg * 8;
        #pragma unroll
        for (int ks = 0; ks < 8; ++ks)
            a[ks] = *reinterpret_cast<const bf16x8*>(xp + ks * 32);
    };
    auto tile = [&](int m, const bf16x8 (&a)[8]) {
        f32x4 acc = {0.f, 0.f, 0.f, 0.f};
        #pragma unroll
        for (int ks = 0; ks < 8; ++ks)
            acc = __builtin_amdgcn_mfma_f32_16x16x32_bf16(a[ks], bfr[ks], acc, 0, 0, 0);
        #pragma unroll
        for (int j = 0; j < 4; ++j) {
            int r = m * 16 + kg * 4 + j;
            if (r < cnt) {
                int t = __shfl(tok[m], kg * 4 + j);
                float w = pw[(size_t)t * NLEV + lvl];
                dst[((size_t)t << 8) + colbase + l15] = w * (acc[j] + bias);
            }
        }
    };

    loadA(0, aA);
    if (nmt > 1) {
        loadA(1, aB);
        tile(0, aA);
        if (nmt > 2) {
            loadA(2, aA);
            tile(1, aB);
            if (nmt > 3) {
                loadA(3, aB);
                tile(2, aA);
                tile(3, aB);
            } else {
                tile(2, aA);
            }
        } else {
            tile(1, aB);
        }
    } else {
        tile(0, aA);
    }
}

// ---------------- Kernel 4: reduce 8 level-buffers -> out ----------------
__global__ __launch_bounds__(256) void reduce_kernel(
    const float* __restrict__ lvlbuf, float* __restrict__ out)
{
    int idx = blockIdx.x * 256 + threadIdx.x;          // float4 index, < 131072
    const float4* lb = reinterpret_cast<const float4*>(lvlbuf);
    float4 s = lb[idx];
    #pragma unroll
    for (int l = 1; l < NLEV; ++l) {
        float4 v = lb[(size_t)l * 131072 + idx];
        s.x += v.x; s.y += v.y; s.z += v.z; s.w += v.w;
    }
    reinterpret_cast<float4*>(out)[idx] = s;
}

extern "C" void kernel_launch(void* const* d_in, const int* in_sizes, int n_in,
                              void* d_out, int out_size, void* d_ws, size_t ws_size,
                              hipStream_t stream) {
    const float* x   = (const float*)d_in[0];
    const float* w1s = (const float*)d_in[1];
    const float* b1s = (const float*)d_in[2];
    const float* w2s = (const float*)d_in[3];
    const float* b2s = (const float*)d_in[4];
    float* out = (float*)d_out;

    // workspace layout
    float* pw             = (float*)d_ws;                          // 64 KB
    int* pc               = (int*)(pw + T_TOKENS * NLEV);          // 8 KB
    int* order            = pc + T_TOKENS;                         // 8 KB
    unsigned* units       = (unsigned*)(order + T_TOKENS);         // 2 KB
    int* ucount           = (int*)(units + 512);                   // 4 B
    unsigned short* xbf   = (unsigned short*)((char*)d_ws + (256 << 10));  // 1 MB
    float* lvlbuf         = (float*)((char*)d_ws + (2 << 20));     // 16 MB @ 2MB
    unsigned short* w2bfT = (unsigned short*)((char*)d_ws + ((size_t)32 << 20));  // 33.5 MB @ 32MB

    fused_kernel<<<NCONV + 512, 256, 0, stream>>>(x, w1s, b1s, w2s, pw, pc, xbf, w2bfT);
    sort_kernel<<<1, 256, 0, stream>>>(pc, order, units, ucount);
    out_kernel<<<2048, 256, 0, stream>>>(xbf, w2bfT, b2s, pw, order, units, ucount, lvlbuf);
    reduce_kernel<<<512, 256, 0, stream>>>(lvlbuf, out);
}